// Round 1
// baseline (951.513 us; speedup 1.0000x reference)
//
#include <hip/hip_runtime.h>

// LigerJSD, beta = 0.5:
//   loss = (1/B) * sum_ij [ 0.5*P*(p - log m) + 0.5*Q*(q - log m) ]
//        = (1/B) * sum_ij [ 0.5*(P*p + Q*q) - m*log(m) ],  m = 0.5*(P+Q)
// B = 4096 rows (fixed by the reference), V = 32000, N = B*V fp32 elements.
// Memory-bound: 1.05 GB read -> ~166 us floor at 6.3 TB/s.

#define BLOCK 256
#define GRID  4096

__device__ __forceinline__ float jsd_elem(float pv, float qv) {
    float P = __expf(pv);
    float Q = __expf(qv);
    float m = 0.5f * (P + Q);
    return 0.5f * (P * pv + Q * qv) - m * __logf(m);
}

__device__ __forceinline__ float block_reduce(float acc) {
    // wave-64 butterfly
    #pragma unroll
    for (int off = 32; off > 0; off >>= 1)
        acc += __shfl_down(acc, off, 64);
    __shared__ float smem[BLOCK / 64];
    const int lane = threadIdx.x & 63;
    const int wave = threadIdx.x >> 6;
    if (lane == 0) smem[wave] = acc;
    __syncthreads();
    float total = 0.0f;
    if (threadIdx.x == 0) {
        #pragma unroll
        for (int w = 0; w < BLOCK / 64; ++w) total += smem[w];
    }
    return total;  // valid only on thread 0
}

__global__ __launch_bounds__(BLOCK) void jsd_partial_kernel(
        const float* __restrict__ p, const float* __restrict__ q,
        float* __restrict__ partials, long long n4) {
    const float4* __restrict__ p4 = (const float4*)p;
    const float4* __restrict__ q4 = (const float4*)q;
    long long idx    = (long long)blockIdx.x * BLOCK + threadIdx.x;
    long long stride = (long long)gridDim.x * BLOCK;

    float acc = 0.0f;
    for (long long i = idx; i < n4; i += stride) {
        float4 a = p4[i];
        float4 b = q4[i];
        acc += jsd_elem(a.x, b.x);
        acc += jsd_elem(a.y, b.y);
        acc += jsd_elem(a.z, b.z);
        acc += jsd_elem(a.w, b.w);
    }
    float total = block_reduce(acc);
    if (threadIdx.x == 0) partials[blockIdx.x] = total;
}

__global__ __launch_bounds__(BLOCK) void jsd_final_kernel(
        const float* __restrict__ partials, int g,
        float* __restrict__ out, float inv_rows) {
    float acc = 0.0f;
    for (int i = threadIdx.x; i < g; i += BLOCK) acc += partials[i];
    float total = block_reduce(acc);
    if (threadIdx.x == 0) out[0] = total * inv_rows;
}

extern "C" void kernel_launch(void* const* d_in, const int* in_sizes, int n_in,
                              void* d_out, int out_size, void* d_ws, size_t ws_size,
                              hipStream_t stream) {
    const float* p = (const float*)d_in[0];
    const float* q = (const float*)d_in[1];
    float* out = (float*)d_out;
    float* partials = (float*)d_ws;  // GRID floats = 16 KB, well under ws_size

    long long n  = (long long)in_sizes[0];   // 4096 * 32000, divisible by 4
    long long n4 = n >> 2;
    const float inv_rows = 1.0f / 4096.0f;   // reference B = 4096

    jsd_partial_kernel<<<GRID, BLOCK, 0, stream>>>(p, q, partials, n4);
    jsd_final_kernel<<<1, BLOCK, 0, stream>>>(partials, GRID, out, inv_rows);
}